// Round 4
// baseline (879.022 us; speedup 1.0000x reference)
//
#include <hip/hip_runtime.h>

typedef __bf16 bf16x8 __attribute__((ext_vector_type(8)));
typedef __bf16 bf16x4 __attribute__((ext_vector_type(4)));
typedef float  f32x4  __attribute__((ext_vector_type(4)));

#define NB 8
#define NC 64
#define NH 256
#define NW 256
#define NT 16     // W tiles
#define WT 16     // core width per WG
#define SEG 32    // steps between neighbor syncs == halo width per side
#define NS 5      // window subtiles: (WT + 2*SEG)/16
#define LDSW 82   // window + conv pad columns, w = wc0-1 .. wc0+80
#define LDSC 72   // ci stride: 144 B rows keep ds_read_b128 16B-aligned

// tanh(x) = 1 - 2/(1+e^{2x}); bounded, branch-free, NaN-free for finite x
__device__ __forceinline__ float fast_tanh(float x) {
    float e = __expf(2.0f * x);
    return 1.0f - 2.0f / (1.0f + e);
}

// 128 WGs = 8 batches x 16 W-tiles; 512 threads = 8 waves -> 2 waves/SIMD.
// Subtile split by parity: waves 0-3 (co-tile wv) own s = {0,2,4} (core s=2,
// they do the Y store); waves 4-7 (co-tile wv-4) own s = {1,3}. Same total
// per-SIMD work as the 4-wave version, but two co-resident waves interleave
// their ds_read -> MFMA -> tanh -> ds_write dependency stalls.
__global__ __launch_bounds__(512, 2)
void spconv_trap(const float* __restrict__ Xg,
                 const float* __restrict__ Wg,
                 const float* __restrict__ Bg,
                 float* __restrict__ Yg,
                 int* __restrict__ flags)
{
    const int b    = blockIdx.x & 7;
    const int t    = blockIdx.x >> 3;
    const int tid  = threadIdx.x;
    const int wv   = tid >> 6;       // 0..7
    const int cot  = wv & 3;         // co-tile
    const bool odd = wv >= 4;        // subtile parity group
    const int sb   = odd ? 1 : 0;    // subtile = 2*j + sb
    const int nsub = odd ? 2 : 3;
    const int lane = tid & 63;
    const int g    = lane >> 4;      // quad
    const int lm   = lane & 15;
    const int w0   = t * WT;
    const int wc0  = w0 - SEG;       // window start

    __shared__ __bf16 buf[2][LDSW][LDSC];  // double-buffered prev row, 23.6 KB

    // ---- A fragments (this wave's co-tile), resident in VGPRs ----
    // chunk c: k-tap = c>>1, ci0 = 32*(c&1)+8g; A[m=lm][q=8g+j]=W[co][ci0+j][k]
    bf16x8 afrag[6];
    {
        const int co = cot * 16 + lm;
        #pragma unroll
        for (int c = 0; c < 6; ++c) {
            const int k = c >> 1, ci0 = 32 * (c & 1) + 8 * g;
            bf16x8 a;
            #pragma unroll
            for (int j = 0; j < 8; ++j)
                a[j] = (__bf16)Wg[(co * NC + ci0 + j) * 3 + k];
            afrag[c] = a;
        }
    }
    float bias_r[4];
    #pragma unroll
    for (int i = 0; i < 4; ++i)
        bias_r[i] = Bg[cot * 16 + 4 * g + i];

    // ---- init: BOTH buffers <- X row 0 over the window (clamped outside) ----
    {
        const int ci = tid & 63;
        for (int r = (tid >> 6); r < LDSW; r += 8) {
            const int w = wc0 - 1 + r;
            float v = (w >= 0 && w < NW)
                    ? Xg[((size_t)(b * NC + ci) * NH + 0) * NW + w] : 0.0f;
            const __bf16 bv = (__bf16)v;
            buf[0][r][ci] = bv;
            buf[1][r][ci] = bv;
        }
    }
    // Y row 0 = X row 0 (exact fp32 passthrough), core columns, even waves
    if (!odd) {
        #pragma unroll
        for (int i = 0; i < 4; ++i) {
            const int co = cot * 16 + 4 * g + i;
            const size_t idx = ((size_t)(b * NC + co) * NH + 0) * NW + w0 + lm;
            Yg[idx] = Xg[idx];
        }
    }

    // per-lane window-column validity for this wave's subtile slots
    bool wok[3];
    #pragma unroll
    for (int j = 0; j < 3; ++j) {
        const int s = 2 * j + sb;
        const int w = wc0 + 16 * s + lm;
        wok[j] = (w >= 0 && w < NW);
    }

    // ping-pong X prefetch registers; preload row 1 into xA
    float xA[3][4], xB[3][4];
    #pragma unroll
    for (int j = 0; j < 3; ++j) if (j < nsub) {
        const int s = 2 * j + sb;
        #pragma unroll
        for (int i = 0; i < 4; ++i) {
            const int co = cot * 16 + 4 * g + i;
            const int w  = wc0 + 16 * s + lm;
            xA[j][i] = wok[j]
                ? Xg[((size_t)(b * NC + co) * NH + 1) * NW + w] : 0.0f;
        }
    }
    __syncthreads();

    const int myflag = b * NT + t;

    // p is a compile-time constant at each call site (body inlined twice per
    // unrolled pair), so LDS buffer selection folds to immediates.
    auto body = [&](int h, int p, float (&xcur)[3][4], float (&xnext)[3][4]) {
        // ---- prefetch X[h+1] at step top: ~1 full step to cover HBM ----
        if (h + 1 < NH) {
            #pragma unroll
            for (int j = 0; j < 3; ++j) if (j < nsub) {
                const int s = 2 * j + sb;
                #pragma unroll
                for (int i = 0; i < 4; ++i) {
                    const int co = cot * 16 + 4 * g + i;
                    const int w  = wc0 + 16 * s + lm;
                    xnext[j][i] = wok[j]
                        ? Xg[((size_t)(b * NC + co) * NH + h + 1) * NW + w] : 0.0f;
                }
            }
        }

        // ---- conv over this wave's subtiles: D = sum_c A_c*B_c, K=192 ----
        float yv[3][4];
        #pragma unroll
        for (int j = 0; j < 3; ++j) if (j < nsub) {
            const int s = 2 * j + sb;
            f32x4 acc = {0.f, 0.f, 0.f, 0.f};
            #pragma unroll
            for (int c = 0; c < 6; ++c) {
                const bf16x8 bfr =
                    *(const bf16x8*)&buf[p][16 * s + lm + (c >> 1)][32 * (c & 1) + 8 * g];
                acc = __builtin_amdgcn_mfma_f32_16x16x32_bf16(afrag[c], bfr, acc, 0, 0, 0);
            }
            #pragma unroll
            for (int i = 0; i < 4; ++i)
                yv[j][i] = xcur[j][i] + fast_tanh(acc[i] + bias_r[i]);
        }
        // ---- store core columns (even waves, j=1 <-> s=2) to global, fp32 ----
        if (!odd) {
            #pragma unroll
            for (int i = 0; i < 4; ++i) {
                const int co = cot * 16 + 4 * g + i;
                Yg[((size_t)(b * NC + co) * NH + h) * NW + w0 + lm] = yv[1][i];
            }
        }

        // ---- write new row into the OTHER buffer (no read-WAR barrier) ----
        #pragma unroll
        for (int j = 0; j < 3; ++j) if (j < nsub) {
            const int s = 2 * j + sb;
            bf16x4 pk;
            #pragma unroll
            for (int i = 0; i < 4; ++i)
                pk[i] = wok[j] ? (__bf16)yv[j][i] : (__bf16)0.0f;
            *(bf16x4*)&buf[p ^ 1][16 * s + lm + 1][cot * 16 + 4 * g] = pk;
        }

        const bool boundary = (h < NH - 1) && ((h & (SEG - 1)) == 0);
        if (boundary) {
            const int k = h >> 5;          // completed segment index, 1..7
            __threadfence();               // publish my Y stores (drains vmcnt)
            __syncthreads();               // all fences done before flag store
            if (tid == 0)
                __hip_atomic_store(&flags[myflag], k,
                                   __ATOMIC_RELEASE, __HIP_MEMORY_SCOPE_AGENT);
            // spin in two different waves so the waits overlap
            if (t > 0 && tid == 64) {
                while (__hip_atomic_load(&flags[myflag - 1], __ATOMIC_ACQUIRE,
                                         __HIP_MEMORY_SCOPE_AGENT) < k)
                    __builtin_amdgcn_s_sleep(2);
            }
            if (t < NT - 1 && tid == 448) {
                while (__hip_atomic_load(&flags[myflag + 1], __ATOMIC_ACQUIRE,
                                         __HIP_MEMORY_SCOPE_AGENT) < k)
                    __builtin_amdgcn_s_sleep(2);
            }
            __syncthreads();
            // refill halo regions of buf[p^1] from neighbors' Y[h], f32x4:
            // 2 sides x 64 ci x 8 w-quads = 1024 tasks, 2 per thread
            for (int idx = tid; idx < 2 * NC * (SEG / 4); idx += 512) {
                const int q    = idx & 7;
                const int ci   = (idx >> 3) & 63;
                const int side = idx >> 9;             // 0 = left, 1 = right
                const bool have = side ? (t < NT - 1) : (t > 0);
                if (have) {
                    const int wq = w0 - SEG + 4 * q + side * (WT + SEG);
                    const int r  = 4 * q + 1 + side * (WT + SEG);
                    const f32x4 v = *(const f32x4*)
                        &Yg[((size_t)(b * NC + ci) * NH + h) * NW + wq];
                    #pragma unroll
                    for (int i2 = 0; i2 < 4; ++i2)
                        buf[p ^ 1][r + i2][ci] = (__bf16)v[i2];
                }
            }
            __syncthreads();
        } else {
            // LDS-only barrier: new-row ds_writes visible, vmcnt NOT drained
            asm volatile("s_waitcnt lgkmcnt(0)" ::: "memory");
            __builtin_amdgcn_sched_barrier(0);
            __builtin_amdgcn_s_barrier();
            __builtin_amdgcn_sched_barrier(0);
        }
    };

    // h odd -> reads buf[0], writes buf[1]; h even -> the reverse.
    // Boundaries (h % 32 == 0) always land in the second body (p = 1).
    for (int h = 1; h < NH; h += 2) {
        body(h, 0, xA, xB);
        if (h + 1 < NH) body(h + 1, 1, xB, xA);
    }
}

extern "C" void kernel_launch(void* const* d_in, const int* in_sizes, int n_in,
                              void* d_out, int out_size, void* d_ws, size_t ws_size,
                              hipStream_t stream)
{
    const float* X  = (const float*)d_in[0];
    const float* Wc = (const float*)d_in[1];
    const float* Bc = (const float*)d_in[2];
    float* Y        = (float*)d_out;
    int* flags      = (int*)d_ws;   // 128 ints; d_ws is poisoned 0xAA -> memset

    hipMemsetAsync(d_ws, 0, NB * NT * sizeof(int), stream);

    dim3 grid(NB * NT);   // 128 WGs x 8 waves: all co-resident, spin-safe
    dim3 block(512);
    hipLaunchKernelGGL(spconv_trap, grid, block, 0, stream, X, Wc, Bc, Y, flags);
}